// Round 7
// baseline (73.114 us; speedup 1.0000x reference)
//
#include <hip/hip_runtime.h>
#include <hip/hip_cooperative_groups.h>
#include <math.h>

namespace cg = cooperative_groups;

#define BB 64
#define NN 2000
#define HH 128
#define NHEAD 8
#define SP 8
#define RPB 250     // rows per block (SP*RPB == NN)

// ---- shared-memory arena (phase-disjoint aliasing) ----
// phase A/B:  pl[250][8] @0 (8000) | wred[8][4][32]f4 @8000 (16384) | lred @24384 (128)
// phase C:    Wns @0 (4096) | lsm @4096 (32) | tmp @4128 (1024) | outf @5152 | fq @5664
//             lq_lds @23296 (512)   [aliases dead wred tail]
// phase D:    red @24512 (16)
#define SM_BYTES 24528

// =========================== device bodies ===========================

__device__ __forceinline__ void body_qk(
    const float* pe, const float* cls, const float* Wqg, const float* Wqf,
    const float* Wql, const float* Wk, int b, int last, int tid,
    float4* sc4, float4* sl4, float* qv, float* qk) {
  if (tid < 32) {
    sc4[tid] = ((const float4*)(cls + b*HH))[tid];
    sl4[tid] = ((const float4*)(pe + ((long)b*NN + last)*HH))[tid];
  }
  __syncthreads();
  if (tid < 128) {
    const float4* wg = (const float4*)(Wqg + tid*HH);
    const float4* wf = (const float4*)(Wqf + tid*HH);
    const float4* wl = (const float4*)(Wql + tid*HH);
    float acc = 0.f;
    #pragma unroll 8
    for (int j = 0; j < 32; j++) {
      float4 g = wg[j], f = wf[j], l = wl[j], c = sc4[j], s = sl4[j];
      acc += g.x*c.x + g.y*c.y + g.z*c.z + g.w*c.w;
      acc += (f.x+l.x)*s.x + (f.y+l.y)*s.y + (f.z+l.z)*s.z + (f.w+l.w)*s.w;
    }
    qv[tid] = acc;
  }
  __syncthreads();
  if (tid < 128) {
    #pragma unroll
    for (int h = 0; h < NHEAD; h++) {
      float a = 0.f;
      #pragma unroll
      for (int d = 0; d < 16; d++)
        a += qv[h*16+d] * Wk[(h*16+d)*HH + tid];
      qk[(b*NHEAD + h)*HH + tid] = a * 0.25f;   // fold 1/sqrt(head_dim)
    }
  }
}

// scores for 250 rows -> pl (LDS), then W/l partial sums -> Wpart/lpart
__device__ __forceinline__ void body_scores_wsum(
    const float* pe, const float* __restrict__ qk, int b, int sp, int last, int tid,
    float (*pl)[NHEAD], float4 (*wred)[4][32], float (*lred)[NHEAD],
    float* Wpart, float* lpart) {
  const int n0 = sp * RPB;
  if (tid < RPB) {
    const int n = n0 + tid;
    const float4* prow = (const float4*)(pe + ((long)b*NN + n)*HH);
    const float4* qk4  = (const float4*)(qk + (long)b*NHEAD*HH);   // uniform -> s_load
    float d[NHEAD];
    #pragma unroll
    for (int h = 0; h < NHEAD; h++) d[h] = 0.f;
    #pragma unroll 2
    for (int j = 0; j < 32; j += 4) {
      float4 v0 = prow[j], v1 = prow[j+1], v2 = prow[j+2], v3 = prow[j+3];
      #pragma unroll
      for (int h = 0; h < NHEAD; h++) {
        float4 q0 = qk4[h*32+j],   q1 = qk4[h*32+j+1];
        float4 q2 = qk4[h*32+j+2], q3 = qk4[h*32+j+3];
        d[h] += v0.x*q0.x + v0.y*q0.y + v0.z*q0.z + v0.w*q0.w
              + v1.x*q1.x + v1.y*q1.y + v1.z*q1.z + v1.w*q1.w
              + v2.x*q2.x + v2.y*q2.y + v2.z*q2.z + v2.w*q2.w
              + v3.x*q3.x + v3.y*q3.y + v3.z*q3.z + v3.w*q3.w;
      }
    }
    const bool live = (n != last);
    float4 p0, p1;
    p0.x = live ? __expf(d[0]) : 0.f;  p0.y = live ? __expf(d[1]) : 0.f;
    p0.z = live ? __expf(d[2]) : 0.f;  p0.w = live ? __expf(d[3]) : 0.f;
    p1.x = live ? __expf(d[4]) : 0.f;  p1.y = live ? __expf(d[5]) : 0.f;
    p1.z = live ? __expf(d[6]) : 0.f;  p1.w = live ? __expf(d[7]) : 0.f;
    ((float4*)pl[tid])[0] = p0;
    ((float4*)pl[tid])[1] = p1;
  }
  __syncthreads();

  const int w = tid >> 6, lane = tid & 63;
  const int st = w*2 + (lane >> 5);       // row-stream 0..7
  const int j4 = lane & 31;
  const float4* peg = (const float4*)(pe + ((long)b*NN + n0)*HH);
  float4 wa[NHEAD];
  float  la[NHEAD];
  #pragma unroll
  for (int h = 0; h < NHEAD; h++) { wa[h] = make_float4(0.f,0.f,0.f,0.f); la[h] = 0.f; }
  #pragma unroll 4
  for (int i = 0; i < 32; i++) {
    const int nl = st + (i << 3);
    if (nl < RPB) {
      float4 v  = peg[nl*32 + j4];
      float4 pa = *(const float4*)&pl[nl][0];
      float4 pb = *(const float4*)&pl[nl][4];
      wa[0].x += pa.x*v.x; wa[0].y += pa.x*v.y; wa[0].z += pa.x*v.z; wa[0].w += pa.x*v.w; la[0] += pa.x;
      wa[1].x += pa.y*v.x; wa[1].y += pa.y*v.y; wa[1].z += pa.y*v.z; wa[1].w += pa.y*v.w; la[1] += pa.y;
      wa[2].x += pa.z*v.x; wa[2].y += pa.z*v.y; wa[2].z += pa.z*v.z; wa[2].w += pa.z*v.w; la[2] += pa.z;
      wa[3].x += pa.w*v.x; wa[3].y += pa.w*v.y; wa[3].z += pa.w*v.z; wa[3].w += pa.w*v.w; la[3] += pa.w;
      wa[4].x += pb.x*v.x; wa[4].y += pb.x*v.y; wa[4].z += pb.x*v.z; wa[4].w += pb.x*v.w; la[4] += pb.x;
      wa[5].x += pb.y*v.x; wa[5].y += pb.y*v.y; wa[5].z += pb.y*v.z; wa[5].w += pb.y*v.w; la[5] += pb.y;
      wa[6].x += pb.z*v.x; wa[6].y += pb.z*v.y; wa[6].z += pb.z*v.z; wa[6].w += pb.z*v.w; la[6] += pb.z;
      wa[7].x += pb.w*v.x; wa[7].y += pb.w*v.y; wa[7].z += pb.w*v.z; wa[7].w += pb.w*v.w; la[7] += pb.w;
    }
  }
  #pragma unroll
  for (int h = 0; h < NHEAD; h++) {
    wa[h].x += __shfl_xor(wa[h].x, 32);
    wa[h].y += __shfl_xor(wa[h].y, 32);
    wa[h].z += __shfl_xor(wa[h].z, 32);
    wa[h].w += __shfl_xor(wa[h].w, 32);
    la[h]   += __shfl_xor(la[h], 32);
  }
  if (lane < 32) {
    #pragma unroll
    for (int h = 0; h < NHEAD; h++) wred[h][w][lane] = wa[h];
  }
  if (lane == 0) {
    #pragma unroll
    for (int h = 0; h < NHEAD; h++) lred[w][h] = la[h];
  }
  __syncthreads();
  const int h2 = tid >> 5, c = tid & 31;
  float4 s0 = wred[h2][0][c], s1 = wred[h2][1][c], s2 = wred[h2][2][c], s3 = wred[h2][3][c];
  float4 s;
  s.x = s0.x + s1.x + s2.x + s3.x;
  s.y = s0.y + s1.y + s2.y + s3.y;
  s.z = s0.z + s1.z + s2.z + s3.z;
  s.w = s0.w + s1.w + s2.w + s3.w;
  ((float4*)(Wpart + ((long)(b*SP + sp)*NHEAD + h2)*HH))[c] = s;
  if (tid < NHEAD)
    lpart[(b*SP + sp)*NHEAD + tid] =
        lred[0][tid] + lred[1][tid] + lred[2][tid] + lred[3][tid];
}

// split-combine + matvec chain; writes lq_dest[0..127] (LDS or global)
__device__ __forceinline__ void body_k34(
    const float* lpart, const float* Wpart, const float* Wv, const float* Wc,
    const float* bc, const float* lWk, int B2, int tid,
    float* Wns, float* lsm, float (*tmp)[HH], float* outf, float* fq,
    float* lq_dest) {
  for (int e = tid; e < NHEAD*HH; e += 256) {
    float a = 0.f;
    #pragma unroll
    for (int s = 0; s < SP; s++) a += Wpart[((long)(B2*SP+s)*NHEAD)*HH + e];
    Wns[e] = a;
  }
  if (tid < NHEAD) {
    float l = 0.f;
    #pragma unroll
    for (int s = 0; s < SP; s++) l += lpart[(B2*SP+s)*NHEAD + tid];
    lsm[tid] = l;
  }
  __syncthreads();
  const int t = tid & 127, half = tid >> 7;
  {
    const int h = t >> 4;
    const float4* wv = (const float4*)(Wv + t*HH);
    const float4* wn = (const float4*)(Wns + h*HH);
    float a = 0.f;
    #pragma unroll 4
    for (int j = half*16; j < half*16 + 16; j++) {
      float4 v = wv[j], nn = wn[j];
      a += v.x*nn.x + v.y*nn.y + v.z*nn.z + v.w*nn.w;
    }
    tmp[half][t] = a;
    __syncthreads();
    if (half == 0) outf[t] = (tmp[0][t] + tmp[1][t]) / lsm[t>>4];
    __syncthreads();
  }
  {
    const float4* wc = (const float4*)(Wc + t*HH);
    const float4* of = (const float4*)outf;
    float a = 0.f;
    #pragma unroll 4
    for (int k = half*16; k < half*16 + 16; k++) {
      float4 v = wc[k], nn = of[k];
      a += v.x*nn.x + v.y*nn.y + v.z*nn.z + v.w*nn.w;
    }
    tmp[half][t] = a;
    __syncthreads();
    if (half == 0) fq[t] = tmp[0][t] + tmp[1][t] + bc[t];
    __syncthreads();
  }
  {
    float a = 0.f;
    #pragma unroll 4
    for (int i = half*64; i < half*64 + 64; i++)
      a += fq[i] * lWk[i*HH + t];
    tmp[half][t] = a;
    __syncthreads();
    if (half == 0)
      lq_dest[t] = (tmp[0][t] + tmp[1][t]) * 0.08838834764831845f;
  }
}

// logits dot, lq source passed as generic pointer (global s_load or LDS broadcast)
__device__ __forceinline__ float body_logit(
    const float* pe, const float* lqp, int b, int n, int last) {
  const float4* prow = (const float4*)(pe + ((long)b*NN + n)*HH);
  const float4* lq4  = (const float4*)lqp;
  float a0 = 0.f, a1 = 0.f, a2 = 0.f, a3 = 0.f;
  #pragma unroll 2
  for (int j = 0; j < 32; j += 4) {
    float4 v0 = prow[j], v1 = prow[j+1], v2 = prow[j+2], v3 = prow[j+3];
    float4 q0 = lq4[j], q1 = lq4[j+1], q2 = lq4[j+2], q3 = lq4[j+3];
    a0 += v0.x*q0.x + v0.y*q0.y + v0.z*q0.z + v0.w*q0.w;
    a1 += v1.x*q1.x + v1.y*q1.y + v1.z*q1.z + v1.w*q1.w;
    a2 += v2.x*q2.x + v2.y*q2.y + v2.z*q2.z + v2.w*q2.w;
    a3 += v3.x*q3.x + v3.y*q3.y + v3.z*q3.z + v3.w*q3.w;
  }
  const float acc = (a0 + a1) + (a2 + a3);
  // exp(10*tanh(x)-10) = exp(-20/(exp(2x)+1))
  return (n != last) ? __expf(-20.f / (__expf(2.f*acc) + 1.f)) : 0.f;
}

// =========================== k1: qk producer ===========================

__global__ __launch_bounds__(128) void k1(
    const float* __restrict__ pe, const float* __restrict__ cls,
    const float* __restrict__ Wqg, const float* __restrict__ Wqf,
    const float* __restrict__ Wql, const float* __restrict__ Wk,
    const int* __restrict__ lp, float* __restrict__ qk) {
  __shared__ float4 sc4[32], sl4[32];
  __shared__ float qv[HH];
  int b = blockIdx.x;
  body_qk(pe, cls, Wqg, Wqf, Wql, Wk, b, lp[b], threadIdx.x, sc4, sl4, qv, qk);
}

// =========================== cooperative mega (2 grid syncs) ===========================

__global__ __launch_bounds__(256, 2) void mega(
    const float* __restrict__ pe, const float* __restrict__ qk,
    const float* __restrict__ Wv, const float* __restrict__ lWk,
    const float* __restrict__ Wc, const float* __restrict__ bc,
    const int* __restrict__ lp, float* __restrict__ out,
    float* __restrict__ Wpart, float* __restrict__ lpart,
    float* __restrict__ psum) {
  cg::grid_group grid = cg::this_grid();
  const int gb = blockIdx.x;
  const int b = gb >> 3, sp = gb & 7;
  const int tid = threadIdx.x;

  __shared__ __align__(16) char smraw[SM_BYTES];
  float  (*pl)[NHEAD]   = reinterpret_cast<float(*)[NHEAD]>(smraw);
  float4 (*wred)[4][32] = reinterpret_cast<float4(*)[4][32]>(smraw + 8000);
  float  (*lred)[NHEAD] = reinterpret_cast<float(*)[NHEAD]>(smraw + 24384);
  float  *Wns           = reinterpret_cast<float*>(smraw);
  float  *lsm           = reinterpret_cast<float*>(smraw + 4096);
  float  (*tmp)[HH]     = reinterpret_cast<float(*)[HH]>(smraw + 4128);
  float  *outf          = reinterpret_cast<float*>(smraw + 5152);
  float  *fq            = reinterpret_cast<float*>(smraw + 5664);
  float  *lq_lds        = reinterpret_cast<float*>(smraw + 23296);
  float  *red           = reinterpret_cast<float*>(smraw + 24512);

  const int last = lp[b];

  // phase A+B: scores -> pl (LDS), weighted sums -> Wpart/lpart
  body_scores_wsum(pe, qk, b, sp, last, tid, pl, wred, lred, Wpart, lpart);
  grid.sync();   // S1: all Wpart/lpart visible

  // phase C: EVERY block redundantly computes its batch's lq into LDS
  body_k34(lpart, Wpart, Wv, Wc, bc, lWk, b, tid, Wns, lsm, tmp, outf, fq, lq_lds);
  __syncthreads();

  // phase D: logits (lq from LDS broadcast) + per-block partial sum
  const int n3 = sp*RPB + tid;
  float e = (tid < RPB) ? body_logit(pe, lq_lds, b, n3, last) : 0.f;
  {
    float s = e;
    #pragma unroll
    for (int d = 1; d < 64; d <<= 1) s += __shfl_xor(s, d);
    if ((tid & 63) == 0) red[tid >> 6] = s;
    __syncthreads();
    if (tid == 0) psum[b*SP + sp] = red[0] + red[1] + red[2] + red[3];
  }
  grid.sync();   // S3: psum visible

  if (tid < RPB) {
    float S = 0.f;
    #pragma unroll
    for (int s = 0; s < SP; s++) S += psum[b*SP + s];
    out[b*NN + n3] = e / S;
  }
}

// =========================== fallback kernels ===========================

__global__ __launch_bounds__(256) void fb_kb(
    const float* __restrict__ pe, const float* __restrict__ qk,
    const int* __restrict__ lp, float* __restrict__ Wpart,
    float* __restrict__ lpart) {
  __shared__ float  pl[RPB][NHEAD];
  __shared__ float4 wred[NHEAD][4][32];
  __shared__ float  lred[4][NHEAD];
  int b = blockIdx.y, sp = blockIdx.x;
  body_scores_wsum(pe, qk, b, sp, lp[b], threadIdx.x, pl, wred, lred, Wpart, lpart);
}

__global__ __launch_bounds__(256) void fb_k34(
    const float* __restrict__ lpart, const float* __restrict__ Wpart,
    const float* __restrict__ Wv, const float* __restrict__ Wc,
    const float* __restrict__ bc, const float* __restrict__ lWk,
    float* __restrict__ lq) {
  __shared__ float Wns[NHEAD*HH];
  __shared__ float lsm[NHEAD];
  __shared__ float tmp[2][HH];
  __shared__ float outf[HH], fq[HH];
  body_k34(lpart, Wpart, Wv, Wc, bc, lWk, blockIdx.x, threadIdx.x,
           Wns, lsm, tmp, outf, fq, lq + blockIdx.x*HH);
}

__global__ __launch_bounds__(256) void fb_kd(
    const float* __restrict__ pe, const float* __restrict__ lq,
    const int* __restrict__ lp, float* __restrict__ eout,
    float* __restrict__ psum) {
  __shared__ float red[4];
  int b = blockIdx.y, sp = blockIdx.x, tid = threadIdx.x;
  int n = sp*RPB + tid;
  float e = (tid < RPB) ? body_logit(pe, lq + (long)b*HH, b, n, lp[b]) : 0.f;
  if (tid < RPB) eout[b*NN + n] = e;
  float s = e;
  #pragma unroll
  for (int d = 1; d < 64; d <<= 1) s += __shfl_xor(s, d);
  if ((tid & 63) == 0) red[tid >> 6] = s;
  __syncthreads();
  if (tid == 0) psum[b*SP + sp] = red[0] + red[1] + red[2] + red[3];
}

__global__ __launch_bounds__(256) void fb_ke(
    const float* __restrict__ eout, const float* __restrict__ psum,
    float* __restrict__ out) {
  int b = blockIdx.y, sp = blockIdx.x, tid = threadIdx.x;
  __shared__ float S;
  if (tid == 0) {
    float a = 0.f;
    #pragma unroll
    for (int s = 0; s < SP; s++) a += psum[b*SP + s];
    S = a;
  }
  __syncthreads();
  int n = sp*RPB + tid;
  if (tid < RPB) out[b*NN + n] = eout[b*NN + n] / S;
}

// =========================== host launch ===========================

extern "C" void kernel_launch(void* const* d_in, const int* in_sizes, int n_in,
                              void* d_out, int out_size, void* d_ws, size_t ws_size,
                              hipStream_t stream) {
  (void)in_sizes; (void)n_in; (void)out_size; (void)ws_size;
  const float* pe   = (const float*)d_in[0];
  const float* cls  = (const float*)d_in[1];
  const float* Wqg  = (const float*)d_in[2];
  const float* Wqf  = (const float*)d_in[3];
  const float* Wql  = (const float*)d_in[4];
  const float* Wk   = (const float*)d_in[5];
  const float* Wv   = (const float*)d_in[6];
  const float* lWk  = (const float*)d_in[7];
  const float* Wc   = (const float*)d_in[8];
  const float* bc   = (const float*)d_in[9];
  const int*   lp   = (const int*)d_in[10];
  float* out = (float*)d_out;
  float* ws  = (float*)d_ws;

  float* qk    = ws;                                 // 64*8*128
  float* Wpart = qk + BB*NHEAD*HH;                   // 64*8*8*128
  float* lpart = Wpart + (size_t)BB*SP*NHEAD*HH;     // 64*8*8
  float* lq    = lpart + BB*SP*NHEAD;                // 64*128 (fallback only)
  float* psum  = lq + BB*HH;                         // 64*8
  float* eout  = psum + BB*SP;                       // 64*2000 (fallback only)

  // capture-safe host-side capability checks
  bool coop_ok = false;
  {
    int dev = 0;
    if (hipGetDevice(&dev) == hipSuccess) {
      int attr = 0, ncu = 0, nb = 0;
      hipDeviceGetAttribute(&attr, hipDeviceAttributeCooperativeLaunch, dev);
      hipDeviceGetAttribute(&ncu, hipDeviceAttributeMultiprocessorCount, dev);
      hipError_t oe = hipOccupancyMaxActiveBlocksPerMultiprocessor(
          &nb, (const void*)mega, 256, 0);
      if (attr && oe == hipSuccess && (long)nb * ncu >= (long)BB*SP)
        coop_ok = true;
    }
  }

  k1<<<dim3(BB), dim3(128), 0, stream>>>(pe, cls, Wqg, Wqf, Wql, Wk, lp, qk);

  if (coop_ok) {
    void* args[] = {
      (void*)&pe, (void*)&qk, (void*)&Wv, (void*)&lWk, (void*)&Wc, (void*)&bc,
      (void*)&lp, (void*)&out, (void*)&Wpart, (void*)&lpart, (void*)&psum
    };
    hipError_t le = hipLaunchCooperativeKernel((const void*)mega, dim3(BB*SP),
                                               dim3(256), args, 0, stream);
    if (le == hipSuccess) return;
  }

  fb_kb<<<dim3(SP, BB), dim3(256), 0, stream>>>(pe, qk, lp, Wpart, lpart);
  fb_k34<<<dim3(BB), dim3(256), 0, stream>>>(lpart, Wpart, Wv, Wc, bc, lWk, lq);
  fb_kd<<<dim3(SP, BB), dim3(256), 0, stream>>>(pe, lq, lp, eout, psum);
  fb_ke<<<dim3(SP, BB), dim3(256), 0, stream>>>(eout, psum, out);
}

// Round 8
// 68.756 us; speedup vs baseline: 1.0634x; 1.0634x over previous
//
#include <hip/hip_runtime.h>
#include <math.h>

#define BB 64
#define NN 2000
#define HH 128
#define NHEAD 8
#define SPB 16           // splits per batch for kB/kD/kE
#define RPB 125          // rows per block (SPB*RPB == NN)

// ---------------- k1qk: qk[b][h][:] , one block per (b,h) ----------------
__global__ __launch_bounds__(64) void k1qk(
    const float* __restrict__ pe, const float* __restrict__ cls,
    const float* __restrict__ Wqg, const float* __restrict__ Wqf,
    const float* __restrict__ Wql, const float* __restrict__ Wk,
    const int* __restrict__ lp, float* __restrict__ qk_out) {
  const int blk = blockIdx.x, b = blk >> 3, h = blk & 7;
  const int t = threadIdx.x;
  __shared__ float4 sc4[32], sl4[32];
  __shared__ float qs[16];
  const int last = lp[b];
  if (t < 32) sc4[t] = ((const float4*)(cls + b*HH))[t];
  else        sl4[t-32] = ((const float4*)(pe + ((long)b*NN + last)*HH))[t-32];
  __syncthreads();
  {
    const int dot = t >> 2, part = t & 3;
    const float4* wg = (const float4*)(Wqg + (h*16+dot)*HH) + part*8;
    const float4* wf = (const float4*)(Wqf + (h*16+dot)*HH) + part*8;
    const float4* wl = (const float4*)(Wql + (h*16+dot)*HH) + part*8;
    float a = 0.f;
    #pragma unroll
    for (int k = 0; k < 8; k++) {
      float4 g = wg[k], f = wf[k], l = wl[k];
      float4 c = sc4[part*8+k], s = sl4[part*8+k];
      a += g.x*c.x + g.y*c.y + g.z*c.z + g.w*c.w;
      a += (f.x+l.x)*s.x + (f.y+l.y)*s.y + (f.z+l.z)*s.z + (f.w+l.w)*s.w;
    }
    a += __shfl_xor(a, 1);
    a += __shfl_xor(a, 2);
    if (part == 0) qs[dot] = a;
  }
  __syncthreads();
  float v0 = 0.f, v1 = 0.f;
  #pragma unroll
  for (int d2 = 0; d2 < 16; d2++) {
    const float* wkr = Wk + (h*16+d2)*HH;
    float q = qs[d2];
    v0 += q * wkr[t];
    v1 += q * wkr[t+64];
  }
  qk_out[(b*NHEAD+h)*HH + t]      = v0 * 0.25f;   // fold 1/sqrt(head_dim)
  qk_out[(b*NHEAD+h)*HH + t + 64] = v1 * 0.25f;
}

// ---------------- kB: scores (full row in regs) + weighted sums ----------------
__global__ __launch_bounds__(128) void kB(
    const float* __restrict__ pe, const float* __restrict__ qk,
    const int* __restrict__ lp, float* __restrict__ Wpart,
    float* __restrict__ lpart) {
  const int b = blockIdx.y, sp = blockIdx.x, tid = threadIdx.x;
  __shared__ float  pl[RPB][NHEAD];
  __shared__ float4 wred[NHEAD][2][32];
  __shared__ float  lred[2][NHEAD];
  const int last = lp[b];
  const int n0 = sp * RPB;

  if (tid < RPB) {
    const int n = n0 + tid;
    const float4* prow = (const float4*)(pe + ((long)b*NN + n)*HH);
    const float4* qk4  = (const float4*)(qk + (long)b*NHEAD*HH);  // uniform -> s_load
    float4 r[32];
    #pragma unroll
    for (int j = 0; j < 32; j++) r[j] = prow[j];        // 32 loads in flight
    float d[NHEAD];
    #pragma unroll
    for (int h = 0; h < NHEAD; h++) d[h] = 0.f;
    #pragma unroll
    for (int j = 0; j < 32; j++) {
      const float4 v = r[j];
      #pragma unroll
      for (int h = 0; h < NHEAD; h++) {
        const float4 q = qk4[h*32 + j];
        d[h] += v.x*q.x + v.y*q.y + v.z*q.z + v.w*q.w;
      }
    }
    const bool live = (n != last);
    #pragma unroll
    for (int h = 0; h < NHEAD; h++) pl[tid][h] = live ? __expf(d[h]) : 0.f;
  }
  __syncthreads();

  // phase B: W[h][:] += p[n][h] * pe[n][:], coalesced re-read (L2-hot)
  const int w = tid >> 6, lane = tid & 63;
  const int st = w*2 + (lane >> 5);     // row stream 0..3
  const int j4 = lane & 31;
  const float4* peg = (const float4*)(pe + ((long)b*NN + n0)*HH);
  float4 wa[NHEAD];
  float  la[NHEAD];
  #pragma unroll
  for (int h = 0; h < NHEAD; h++) { wa[h] = make_float4(0.f,0.f,0.f,0.f); la[h] = 0.f; }
  #pragma unroll 4
  for (int i = 0; i < 32; i++) {
    const int nl = st + (i << 2);
    if (nl < RPB) {
      float4 v  = peg[nl*32 + j4];
      float4 pa = *(const float4*)&pl[nl][0];
      float4 pb = *(const float4*)&pl[nl][4];
      wa[0].x += pa.x*v.x; wa[0].y += pa.x*v.y; wa[0].z += pa.x*v.z; wa[0].w += pa.x*v.w; la[0] += pa.x;
      wa[1].x += pa.y*v.x; wa[1].y += pa.y*v.y; wa[1].z += pa.y*v.z; wa[1].w += pa.y*v.w; la[1] += pa.y;
      wa[2].x += pa.z*v.x; wa[2].y += pa.z*v.y; wa[2].z += pa.z*v.z; wa[2].w += pa.z*v.w; la[2] += pa.z;
      wa[3].x += pa.w*v.x; wa[3].y += pa.w*v.y; wa[3].z += pa.w*v.z; wa[3].w += pa.w*v.w; la[3] += pa.w;
      wa[4].x += pb.x*v.x; wa[4].y += pb.x*v.y; wa[4].z += pb.x*v.z; wa[4].w += pb.x*v.w; la[4] += pb.x;
      wa[5].x += pb.y*v.x; wa[5].y += pb.y*v.y; wa[5].z += pb.y*v.z; wa[5].w += pb.y*v.w; la[5] += pb.y;
      wa[6].x += pb.z*v.x; wa[6].y += pb.z*v.y; wa[6].z += pb.z*v.z; wa[6].w += pb.z*v.w; la[6] += pb.z;
      wa[7].x += pb.w*v.x; wa[7].y += pb.w*v.y; wa[7].z += pb.w*v.z; wa[7].w += pb.w*v.w; la[7] += pb.w;
    }
  }
  #pragma unroll
  for (int h = 0; h < NHEAD; h++) {     // merge the two row-half streams
    wa[h].x += __shfl_xor(wa[h].x, 32);
    wa[h].y += __shfl_xor(wa[h].y, 32);
    wa[h].z += __shfl_xor(wa[h].z, 32);
    wa[h].w += __shfl_xor(wa[h].w, 32);
    la[h]   += __shfl_xor(la[h], 32);
  }
  if (lane < 32) {
    #pragma unroll
    for (int h = 0; h < NHEAD; h++) wred[h][w][lane] = wa[h];
  }
  if (lane == 0) {
    #pragma unroll
    for (int h = 0; h < NHEAD; h++) lred[w][h] = la[h];
  }
  __syncthreads();
  {
    const int h2 = tid >> 4, c0 = tid & 15;
    float4* Wo = (float4*)(Wpart + ((long)(b*SPB + sp)*NHEAD + h2)*HH);
    #pragma unroll
    for (int k = 0; k < 2; k++) {
      const int c = c0 + k*16;
      float4 s0 = wred[h2][0][c], s1 = wred[h2][1][c];
      float4 s;
      s.x = s0.x + s1.x; s.y = s0.y + s1.y; s.z = s0.z + s1.z; s.w = s0.w + s1.w;
      Wo[c] = s;
    }
  }
  if (tid < NHEAD)
    lpart[(b*SPB + sp)*NHEAD + tid] = lred[0][tid] + lred[1][tid];
}

// ---------------- kC: combine splits + matvec chain -> lq ----------------
__global__ __launch_bounds__(256) void kC(
    const float* __restrict__ lpart, const float* __restrict__ Wpart,
    const float* __restrict__ Wv, const float* __restrict__ Wc,
    const float* __restrict__ bc, const float* __restrict__ lWk,
    float* __restrict__ lq) {
  const int b = blockIdx.x, tid = threadIdx.x;
  __shared__ float Wns[NHEAD*HH];
  __shared__ float lsm[NHEAD];
  __shared__ float tmp[2][HH];
  __shared__ float outf[HH], fq[HH];
  for (int e = tid; e < NHEAD*HH; e += 256) {
    float a = 0.f;
    #pragma unroll 4
    for (int s = 0; s < SPB; s++) a += Wpart[((long)(b*SPB+s)*NHEAD)*HH + e];
    Wns[e] = a;
  }
  if (tid < NHEAD) {
    float l = 0.f;
    #pragma unroll
    for (int s = 0; s < SPB; s++) l += lpart[(b*SPB+s)*NHEAD + tid];
    lsm[tid] = l;
  }
  __syncthreads();
  const int t = tid & 127, half = tid >> 7;
  {
    const int h = t >> 4;
    const float4* wv = (const float4*)(Wv + t*HH);
    const float4* wn = (const float4*)(Wns + h*HH);
    float a = 0.f;
    #pragma unroll 4
    for (int j = half*16; j < half*16 + 16; j++) {
      float4 v = wv[j], nn = wn[j];
      a += v.x*nn.x + v.y*nn.y + v.z*nn.z + v.w*nn.w;
    }
    tmp[half][t] = a;
    __syncthreads();
    if (half == 0) outf[t] = (tmp[0][t] + tmp[1][t]) / lsm[t>>4];
    __syncthreads();
  }
  {
    const float4* wc = (const float4*)(Wc + t*HH);
    const float4* of = (const float4*)outf;
    float a = 0.f;
    #pragma unroll 4
    for (int k = half*16; k < half*16 + 16; k++) {
      float4 v = wc[k], nn = of[k];
      a += v.x*nn.x + v.y*nn.y + v.z*nn.z + v.w*nn.w;
    }
    tmp[half][t] = a;
    __syncthreads();
    if (half == 0) fq[t] = tmp[0][t] + tmp[1][t] + bc[t];
    __syncthreads();
  }
  {
    float a = 0.f;
    #pragma unroll 4
    for (int i = half*64; i < half*64 + 64; i++)
      a += fq[i] * lWk[i*HH + t];
    tmp[half][t] = a;
    __syncthreads();
    if (half == 0)
      lq[b*HH + t] = (tmp[0][t] + tmp[1][t]) * 0.08838834764831845f;  // 1/sqrt(128)
  }
}

// ---------------- kD: logits (full row in regs) -> unnormalized e + psum ----------------
__global__ __launch_bounds__(128) void kD(
    const float* __restrict__ pe, const float* __restrict__ lq,
    const int* __restrict__ lp, float* __restrict__ out,
    float* __restrict__ psum) {
  const int b = blockIdx.y, sp = blockIdx.x, tid = threadIdx.x;
  __shared__ float red[2];
  const int last = lp[b];
  const int n = sp*RPB + tid;
  float e = 0.f;
  if (tid < RPB) {
    const float4* prow = (const float4*)(pe + ((long)b*NN + n)*HH);
    const float4* lq4  = (const float4*)(lq + (long)b*HH);   // uniform -> s_load
    float4 r[32];
    #pragma unroll
    for (int j = 0; j < 32; j++) r[j] = prow[j];
    float a0 = 0.f, a1 = 0.f, a2 = 0.f, a3 = 0.f;
    #pragma unroll
    for (int j = 0; j < 32; j += 4) {
      float4 q0 = lq4[j], q1 = lq4[j+1], q2 = lq4[j+2], q3 = lq4[j+3];
      a0 += r[j].x*q0.x + r[j].y*q0.y + r[j].z*q0.z + r[j].w*q0.w;
      a1 += r[j+1].x*q1.x + r[j+1].y*q1.y + r[j+1].z*q1.z + r[j+1].w*q1.w;
      a2 += r[j+2].x*q2.x + r[j+2].y*q2.y + r[j+2].z*q2.z + r[j+2].w*q2.w;
      a3 += r[j+3].x*q3.x + r[j+3].y*q3.y + r[j+3].z*q3.z + r[j+3].w*q3.w;
    }
    const float acc = (a0 + a1) + (a2 + a3);
    // exp(10*tanh(x)-10) = exp(-20/(exp(2x)+1))
    e = (n != last) ? __expf(-20.f / (__expf(2.f*acc) + 1.f)) : 0.f;
    out[b*NN + n] = e;    // unnormalized; kE scales in place
  }
  float s = e;
  #pragma unroll
  for (int d = 1; d < 64; d <<= 1) s += __shfl_xor(s, d);
  if ((tid & 63) == 0) red[tid >> 6] = s;
  __syncthreads();
  if (tid == 0) psum[b*SPB + sp] = red[0] + red[1];
}

// ---------------- kE: in-place scale ----------------
__global__ __launch_bounds__(128) void kE(
    const float* __restrict__ psum, float* __restrict__ out) {
  const int b = blockIdx.y, sp = blockIdx.x, tid = threadIdx.x;
  float S = 0.f;
  #pragma unroll
  for (int s = 0; s < SPB; s++) S += psum[b*SPB + s];   // uniform s_loads
  const float inv = 1.f / S;
  const int n = sp*RPB + tid;
  if (tid < RPB) out[b*NN + n] *= inv;
}

// ---------------- host launch ----------------
extern "C" void kernel_launch(void* const* d_in, const int* in_sizes, int n_in,
                              void* d_out, int out_size, void* d_ws, size_t ws_size,
                              hipStream_t stream) {
  (void)in_sizes; (void)n_in; (void)out_size; (void)ws_size;
  const float* pe   = (const float*)d_in[0];
  const float* cls  = (const float*)d_in[1];
  const float* Wqg  = (const float*)d_in[2];
  const float* Wqf  = (const float*)d_in[3];
  const float* Wql  = (const float*)d_in[4];
  const float* Wk   = (const float*)d_in[5];
  const float* Wv   = (const float*)d_in[6];
  const float* lWk  = (const float*)d_in[7];
  const float* Wc   = (const float*)d_in[8];
  const float* bc   = (const float*)d_in[9];
  const int*   lp   = (const int*)d_in[10];
  float* out = (float*)d_out;
  float* ws  = (float*)d_ws;

  float* qk    = ws;                                  // 64*8*128
  float* Wpart = qk + BB*NHEAD*HH;                    // 64*16*8*128
  float* lpart = Wpart + (size_t)BB*SPB*NHEAD*HH;     // 64*16*8
  float* lq    = lpart + BB*SPB*NHEAD;                // 64*128
  float* psum  = lq + BB*HH;                          // 64*16

  k1qk<<<dim3(BB*NHEAD), dim3(64), 0, stream>>>(pe, cls, Wqg, Wqf, Wql, Wk, lp, qk);
  kB<<<dim3(SPB, BB), dim3(128), 0, stream>>>(pe, qk, lp, Wpart, lpart);
  kC<<<dim3(BB), dim3(256), 0, stream>>>(lpart, Wpart, Wv, Wc, bc, lWk, lq);
  kD<<<dim3(SPB, BB), dim3(128), 0, stream>>>(pe, lq, lp, out, psum);
  kE<<<dim3(SPB, BB), dim3(128), 0, stream>>>(psum, out);
}